// Round 16
// baseline (96.883 us; speedup 1.0000x reference)
//
#include <hip/hip_runtime.h>
#include <math.h>

#define DIM      4096
#define KSEL     2048
#define NTHREADS 256
#define VPT      16            // DIM / NTHREADS
#define LO_BITS  0x3D800000u   // 0.0625 — threshold search window lo
#define BSHIFT   17            // 2^17-wide buckets; region >= bin 255 counted in regs
#define CAP      256           // candidate list capacity

typedef float vfloat4 __attribute__((ext_vector_type(4)));
typedef float f32x2   __attribute__((ext_vector_type(2)));

#if __has_builtin(__builtin_elementwise_fma)
#define FMA2(a, b, c) __builtin_elementwise_fma((a), (b), (c))
#else
__device__ __forceinline__ f32x2 FMA2(f32x2 a, f32x2 b, f32x2 c) {
    f32x2 d;
    d.x = __builtin_fmaf(a.x, b.x, c.x);
    d.y = __builtin_fmaf(a.y, b.y, c.y);
    return d;
}
#endif

// ---- bit-exact XLA-CPU silu over a pair (R4-verified pipeline, packed) ----
// absmax == 0.0 verified rounds 4-15. DO NOT MODIFY.
__device__ __forceinline__ f32x2 silu2_ref(f32x2 x) {
    const f32x2 L2E  = {1.44269504088896341f, 1.44269504088896341f};
    const f32x2 HALF = {0.5f, 0.5f};
    const f32x2 C1   = {0.693359375f, 0.693359375f};
    const f32x2 NC2  = {2.12194440e-4f, 2.12194440e-4f};   // == -C2
    const f32x2 P0   = {1.9875691500e-4f, 1.9875691500e-4f};
    const f32x2 P1   = {1.3981999507e-3f, 1.3981999507e-3f};
    const f32x2 P2   = {8.3334519073e-3f, 8.3334519073e-3f};
    const f32x2 P3   = {4.1665795894e-2f, 4.1665795894e-2f};
    const f32x2 P4   = {1.6666665459e-1f, 1.6666665459e-1f};
    const f32x2 P5   = {5.0000001201e-1f, 5.0000001201e-1f};
    const f32x2 ONE  = {1.0f, 1.0f};

    f32x2 nx = -x;
    f32x2 z0 = FMA2(nx, L2E, HALF);
    f32x2 fx;
    fx.x = floorf(z0.x);
    fx.y = floorf(z0.y);
    f32x2 t  = fx * C1;                  // exact product
    f32x2 r  = nx - t;
    r = FMA2(fx, NC2, r);
    f32x2 zz = r * r;
    f32x2 y  = P0;
    y = FMA2(y, r, P1);
    y = FMA2(y, r, P2);
    y = FMA2(y, r, P3);
    y = FMA2(y, r, P4);
    y = FMA2(y, r, P5);
    y = FMA2(y, zz, r);
    y = y + ONE;
    int n0 = (int)fx.x;
    int n1 = (int)fx.y;
    f32x2 sc;
    sc.x = __int_as_float((n0 + 127) << 23);
    sc.y = __int_as_float((n1 + 127) << 23);
    f32x2 e   = y * sc;                  // exact (power-of-2 scale)
    f32x2 den = e + ONE;
    f32x2 s;
    s.x = __fdiv_rn(1.0f, den.x);
    s.y = __fdiv_rn(1.0f, den.y);
    return x * s;
}

__global__ __launch_bounds__(NTHREADS) void topk_silu_kernel(
    const float* __restrict__ x, float* __restrict__ out)
{
    const int tid  = threadIdx.x;
    const int lane = tid & 63;
    const int wave = tid >> 6;
    const int grp  = wave >> 1;          // wave-pair replica index

    const float4* __restrict__ xr4 =
        reinterpret_cast<const float4*>(x + (size_t)blockIdx.x * DIM);
    vfloat4* __restrict__ or4 =
        reinterpret_cast<vfloat4*>(out + (size_t)blockIdx.x * DIM);

    __shared__ int      hist[2][256];    // 2-way wave-pair replicated
    __shared__ int      wred[4];
    __shared__ int      wscan[4];
    __shared__ unsigned s_dig;
    __shared__ int      s_krem;
    __shared__ int      s_nb;
    __shared__ int      s_found;
    __shared__ unsigned s_thr;
    __shared__ int      s_cnt;
    __shared__ unsigned list[CAP];

    hist[0][tid] = 0;
    hist[1][tid] = 0;
    if (tid == 0) { s_found = 0; s_cnt = 0; s_thr = 0xFFFFFFFFu; }
    __syncthreads();                                       // B0: hist ready

    // ---- fused: load + packed silu + histogram (hot hi-region in regs) ----
    // bins 0..254: [LO + b*2^17, LO + (b+1)*2^17) ; region >= LO+255*2^17: nhi
    unsigned hb[VPT];
    int nhi = 0;
    #pragma unroll
    for (int j = 0; j < 4; ++j) {
        float4 v = xr4[j * NTHREADS + tid];
        f32x2 p0 = {v.x, v.y};
        f32x2 p1 = {v.z, v.w};
        f32x2 h0 = silu2_ref(p0);
        f32x2 h1 = silu2_ref(p1);
        float hs[4] = {h0.x, h0.y, h1.x, h1.y};
        #pragma unroll
        for (int c4 = 0; c4 < 4; ++c4) {
            unsigned h = __float_as_uint(hs[c4]);
            hb[j*4+c4] = h;
            unsigned k = h & 0x7FFFFFFFu;
            if (k >= LO_BITS) {
                unsigned bk = (k - LO_BITS) >> BSHIFT;
                if (bk >= 255u) ++nhi;                     // hot region: no LDS
                else atomicAdd(&hist[grp][bk], 1);
            }
        }
    }
    #pragma unroll
    for (int off = 32; off; off >>= 1) nhi += __shfl_xor(nhi, off);
    if (lane == 0) wred[wave] = nhi;
    __syncthreads();                                       // B1: hist + nhi done
    const int n_hi = wred[0] + wred[1] + wred[2] + wred[3];

    // ---- suffix scan over buckets: s = count(keys >= bucket start) ----
    const int c = hist[0][tid] + hist[1][tid];             // c==0 at tid 255
    int s = c;
    #pragma unroll
    for (int off = 1; off < 64; off <<= 1) {
        int t = __shfl_down(s, off);
        if (lane + off < 64) s += t;
    }
    if (lane == 0) wscan[wave] = s;
    __syncthreads();                                       // B2
    #pragma unroll
    for (int w = 0; w < 4; ++w)
        if (w > wave) s += wscan[w];
    s += n_hi;

    if (s >= KSEL && s - c < KSEL) {       // K-th largest lands here (c>0 -> tid<255)
        s_dig   = (unsigned)tid;
        s_krem  = KSEL - (s - c);
        s_nb    = c;
        s_found = 1;
    }
    __syncthreads();                                       // B3

    unsigned thr_bits;
    if (s_found && s_nb <= CAP) {
        // ---- fast path: exact rank among the few bucket candidates ----
        const unsigned bsel = s_dig;                       // < 255 guaranteed
        const int      krem = s_krem;
        const int      nb   = s_nb;
        #pragma unroll
        for (int q = 0; q < VPT; ++q) {
            unsigned k = hb[q] & 0x7FFFFFFFu;
            if (k >= LO_BITS && ((k - LO_BITS) >> BSHIFT) == bsel) {
                int idx = atomicAdd(&s_cnt, 1);
                list[idx] = k;
            }
        }
        __syncthreads();                                   // B4
        if (tid < nb) {
            unsigned ki = list[tid];
            int rk = 0;
            for (int j = 0; j < nb; ++j) rk += (list[j] > ki) ? 1 : 0;
            if (rk < krem) atomicMin(&s_thr, ki);          // ties all kept
        }
        __syncthreads();                                   // B5
        thr_bits = s_thr;
    } else {
        // ---- fallback: full 4-pass radix select (distribution-free) ----
        // covers n_hi >= KSEL (no bucket found) and oversized buckets
        unsigned prefix = 0;
        int      krem   = KSEL;
        #pragma unroll 1
        for (int pass = 0; pass < 4; ++pass) {
            const int shift = 24 - pass * 8;
            hist[0][tid] = 0;
            __syncthreads();
            const unsigned himask =
                (pass == 0) ? 0u : (0xFFFFFFFFu << (shift + 8));
            #pragma unroll
            for (int q = 0; q < VPT; ++q) {
                unsigned k = hb[q] & 0x7FFFFFFFu;
                if ((k & himask) == prefix)
                    atomicAdd(&hist[0][(k >> shift) & 255u], 1);
            }
            __syncthreads();
            int cc = hist[0][tid];
            int ss = cc;
            #pragma unroll
            for (int off = 1; off < 64; off <<= 1) {
                int t = __shfl_down(ss, off);
                if (lane + off < 64) ss += t;
            }
            if (lane == 0) wscan[wave] = ss;
            __syncthreads();
            #pragma unroll
            for (int w = 0; w < 4; ++w)
                if (w > wave) ss += wscan[w];
            if (ss >= krem && ss - cc < krem) {
                s_dig  = (unsigned)tid;
                s_krem = krem - (ss - cc);
            }
            __syncthreads();
            prefix |= s_dig << shift;
            krem    = s_krem;
        }
        thr_bits = prefix;
    }

    // ---- write: keep iff |h| >= thr; NT stores (R14-verified win) ----
    #pragma unroll
    for (int j = 0; j < 4; ++j) {
        vfloat4 o;
        #pragma unroll
        for (int c4 = 0; c4 < 4; ++c4) {
            unsigned h = hb[j*4+c4];
            o[c4] = ((h & 0x7FFFFFFFu) >= thr_bits) ? __uint_as_float(h) : 0.0f;
        }
        __builtin_nontemporal_store(o, &or4[j * NTHREADS + tid]);
    }
}

extern "C" void kernel_launch(void* const* d_in, const int* in_sizes, int n_in,
                              void* d_out, int out_size, void* d_ws, size_t ws_size,
                              hipStream_t stream) {
    const float* x   = (const float*)d_in[0];
    float*       out = (float*)d_out;
    const int rows = in_sizes[0] / DIM;   // 4 * 4096 = 16384
    topk_silu_kernel<<<rows, NTHREADS, 0, stream>>>(x, out);
}

// Round 17
// 92.757 us; speedup vs baseline: 1.0445x; 1.0445x over previous
//
#include <hip/hip_runtime.h>
#include <math.h>

#define DIM      4096
#define KSEL     2048
#define NTHREADS 256
#define VPT      16            // DIM / NTHREADS
#define LO_BITS  0x3D800000u   // 0.0625 — threshold search window lo
#define BSHIFT   17            // 2^17-wide buckets; bin 255 clamps to +inf
#define CAP      256           // candidate list capacity

typedef float vfloat4 __attribute__((ext_vector_type(4)));
typedef float f32x2   __attribute__((ext_vector_type(2)));

#if __has_builtin(__builtin_elementwise_fma)
#define FMA2(a, b, c) __builtin_elementwise_fma((a), (b), (c))
#else
__device__ __forceinline__ f32x2 FMA2(f32x2 a, f32x2 b, f32x2 c) {
    f32x2 d;
    d.x = __builtin_fmaf(a.x, b.x, c.x);
    d.y = __builtin_fmaf(a.y, b.y, c.y);
    return d;
}
#endif

// ---- bit-exact XLA-CPU silu over a pair (R4-verified pipeline, packed) ----
// absmax == 0.0 verified rounds 4-16. DO NOT MODIFY.
__device__ __forceinline__ f32x2 silu2_ref(f32x2 x) {
    const f32x2 L2E  = {1.44269504088896341f, 1.44269504088896341f};
    const f32x2 HALF = {0.5f, 0.5f};
    const f32x2 C1   = {0.693359375f, 0.693359375f};
    const f32x2 NC2  = {2.12194440e-4f, 2.12194440e-4f};   // == -C2
    const f32x2 P0   = {1.9875691500e-4f, 1.9875691500e-4f};
    const f32x2 P1   = {1.3981999507e-3f, 1.3981999507e-3f};
    const f32x2 P2   = {8.3334519073e-3f, 8.3334519073e-3f};
    const f32x2 P3   = {4.1665795894e-2f, 4.1665795894e-2f};
    const f32x2 P4   = {1.6666665459e-1f, 1.6666665459e-1f};
    const f32x2 P5   = {5.0000001201e-1f, 5.0000001201e-1f};
    const f32x2 ONE  = {1.0f, 1.0f};

    f32x2 nx = -x;                       // exact
    f32x2 z0 = FMA2(nx, L2E, HALF);
    f32x2 fx;
    fx.x = floorf(z0.x);
    fx.y = floorf(z0.y);
    f32x2 t  = fx * C1;                  // exact product
    f32x2 r  = nx - t;                   // == __fsub_rn (t exact)
    r = FMA2(fx, NC2, r);
    f32x2 zz = r * r;
    f32x2 y  = P0;
    y = FMA2(y, r, P1);
    y = FMA2(y, r, P2);
    y = FMA2(y, r, P3);
    y = FMA2(y, r, P4);
    y = FMA2(y, r, P5);
    y = FMA2(y, zz, r);
    y = y + ONE;
    int n0 = (int)fx.x;
    int n1 = (int)fx.y;
    f32x2 sc;
    sc.x = __int_as_float((n0 + 127) << 23);
    sc.y = __int_as_float((n1 + 127) << 23);
    f32x2 e   = y * sc;                  // exact (power-of-2 scale)
    f32x2 den = e + ONE;
    f32x2 s;
    s.x = __fdiv_rn(1.0f, den.x);
    s.y = __fdiv_rn(1.0f, den.y);
    return x * s;
}

__global__ __launch_bounds__(NTHREADS) void topk_silu_kernel(
    const float* __restrict__ x, float* __restrict__ out)
{
    const int tid  = threadIdx.x;
    const int lane = tid & 63;
    const int wave = tid >> 6;

    const float4* __restrict__ xr4 =
        reinterpret_cast<const float4*>(x + (size_t)blockIdx.x * DIM);
    vfloat4* __restrict__ or4 =
        reinterpret_cast<vfloat4*>(out + (size_t)blockIdx.x * DIM);

    __shared__ int      hist[256];
    __shared__ int      wscan[4];
    __shared__ unsigned s_dig;
    __shared__ int      s_krem;
    __shared__ int      s_nb;
    __shared__ int      s_found;
    __shared__ unsigned s_thr;
    __shared__ int      s_cnt;
    __shared__ unsigned list[CAP];

    hist[tid] = 0;
    if (tid == 0) { s_found = 0; s_cnt = 0; s_thr = 0xFFFFFFFFu; }
    __syncthreads();                                       // B0: hist ready

    // ---- fused: load + bit-exact packed silu + clamped bucket histogram ----
    // bin b<255: [LO + b*2^17, LO + (b+1)*2^17);  bin 255: [LO + 255*2^17, inf)
    unsigned hb[VPT];
    #pragma unroll
    for (int j = 0; j < 4; ++j) {
        float4 v = xr4[j * NTHREADS + tid];
        f32x2 p0 = {v.x, v.y};
        f32x2 p1 = {v.z, v.w};
        f32x2 h0 = silu2_ref(p0);
        f32x2 h1 = silu2_ref(p1);
        float hs[4] = {h0.x, h0.y, h1.x, h1.y};
        #pragma unroll
        for (int c4 = 0; c4 < 4; ++c4) {
            unsigned h = __float_as_uint(hs[c4]);
            hb[j*4+c4] = h;
            unsigned k = h & 0x7FFFFFFFu;
            if (k >= LO_BITS) {
                unsigned bk = (k - LO_BITS) >> BSHIFT;
                if (bk > 255u) bk = 255u;
                atomicAdd(&hist[bk], 1);
            }
        }
    }
    __syncthreads();                                       // B1: hist complete

    // ---- suffix scan over 256 buckets: s = count(keys >= bucket start) ----
    const int c = hist[tid];
    int s = c;
    #pragma unroll
    for (int off = 1; off < 64; off <<= 1) {
        int t = __shfl_down(s, off);
        if (lane + off < 64) s += t;
    }
    if (lane == 0) wscan[wave] = s;
    __syncthreads();                                       // B2
    #pragma unroll
    for (int w = 0; w < 4; ++w)
        if (w > wave) s += wscan[w];

    if (s >= KSEL && s - c < KSEL) {       // K-th largest lands in this bucket
        s_dig   = (unsigned)tid;
        s_krem  = KSEL - (s - c);
        s_nb    = c;
        s_found = 1;
    }
    __syncthreads();                                       // B3

    unsigned thr_bits;
    if (s_found && s_nb <= CAP) {
        // ---- fast path: exact rank among the few bucket candidates ----
        // (if threshold bucket were bin 255, nb >= krem = 2048 > CAP -> fallback)
        const unsigned bsel = s_dig;
        const int      krem = s_krem;
        const int      nb   = s_nb;
        #pragma unroll
        for (int q = 0; q < VPT; ++q) {
            unsigned k = hb[q] & 0x7FFFFFFFu;
            if (k >= LO_BITS) {
                unsigned bk = (k - LO_BITS) >> BSHIFT;
                if (bk > 255u) bk = 255u;
                if (bk == bsel) {
                    int idx = atomicAdd(&s_cnt, 1);
                    list[idx] = k;
                }
            }
        }
        __syncthreads();                                   // B4
        if (tid < nb) {
            unsigned ki = list[tid];
            int rk = 0;
            for (int j = 0; j < nb; ++j) rk += (list[j] > ki) ? 1 : 0;
            if (rk < krem) atomicMin(&s_thr, ki);          // ties all kept
        }
        __syncthreads();                                   // B5
        thr_bits = s_thr;
    } else {
        // ---- fallback: full 4-pass radix select (distribution-free) ----
        unsigned prefix = 0;
        int      krem   = KSEL;
        #pragma unroll 1
        for (int pass = 0; pass < 4; ++pass) {
            const int shift = 24 - pass * 8;
            hist[tid] = 0;
            __syncthreads();
            const unsigned himask =
                (pass == 0) ? 0u : (0xFFFFFFFFu << (shift + 8));
            #pragma unroll
            for (int q = 0; q < VPT; ++q) {
                unsigned k = hb[q] & 0x7FFFFFFFu;
                if ((k & himask) == prefix)
                    atomicAdd(&hist[(k >> shift) & 255u], 1);
            }
            __syncthreads();
            int cc = hist[tid];
            int ss = cc;
            #pragma unroll
            for (int off = 1; off < 64; off <<= 1) {
                int t = __shfl_down(ss, off);
                if (lane + off < 64) ss += t;
            }
            if (lane == 0) wscan[wave] = ss;
            __syncthreads();
            #pragma unroll
            for (int w = 0; w < 4; ++w)
                if (w > wave) ss += wscan[w];
            if (ss >= krem && ss - cc < krem) {
                s_dig  = (unsigned)tid;
                s_krem = krem - (ss - cc);
            }
            __syncthreads();
            prefix |= s_dig << shift;
            krem    = s_krem;
        }
        thr_bits = prefix;
    }

    // ---- write: keep iff |h| >= thr; NT stores (R14-verified win) ----
    #pragma unroll
    for (int j = 0; j < 4; ++j) {
        vfloat4 o;
        #pragma unroll
        for (int c4 = 0; c4 < 4; ++c4) {
            unsigned h = hb[j*4+c4];
            o[c4] = ((h & 0x7FFFFFFFu) >= thr_bits) ? __uint_as_float(h) : 0.0f;
        }
        __builtin_nontemporal_store(o, &or4[j * NTHREADS + tid]);
    }
}

extern "C" void kernel_launch(void* const* d_in, const int* in_sizes, int n_in,
                              void* d_out, int out_size, void* d_ws, size_t ws_size,
                              hipStream_t stream) {
    const float* x   = (const float*)d_in[0];
    float*       out = (float*)d_out;
    const int rows = in_sizes[0] / DIM;   // 4 * 4096 = 16384
    topk_silu_kernel<<<rows, NTHREADS, 0, stream>>>(x, out);
}